// Round 8
// baseline (96.873 us; speedup 1.0000x reference)
//
#include <hip/hip_runtime.h>
#include <hip/hip_fp16.h>
#include <math.h>

typedef __attribute__((ext_vector_type(8))) _Float16 f16x8;
typedef __attribute__((ext_vector_type(4))) float f32x4;

// x (4,64,64,256) f32 | offset_w (3,3,256,27) | offset_b (27) | dcn_weight (256,256,3,3)
// out (4,64,64,256) f32
// ws layout (bytes):
#define XP_OFF   0                        // x_p f16 [4][67][67][256], pad top/left 1, bot/right 2
#define XP_BYTES (4*67*67*256*2)          // 9,193,472
#define WT_OFF   XP_BYTES                 // W_t f16 [256 oc][2304 k], k = t*256+c
#define WT_BYTES (2304*256*2)
#define WOT_OFF  (WT_OFF + WT_BYTES)      // W_o_t f16 [32 oc][2304 k]
#define WOT_BYTES (2304*32*2)
#define OM_OFF   (WOT_OFF + WOT_BYTES)    // om f32 [16384][32]
#define OM_BYTES (16384*32*4)
#define V_OFF    (OM_OFF + OM_BYTES)      // V f16 [16384 px][2304 k]
#define V_BYTES  ((size_t)16384*2304*2)   // 75,497,472
#define P_OFF    (V_OFF + V_BYTES)        // K-split partials f32 [2][16384][256]
#define P_BYTES  ((size_t)2*16384*256*4)  // 33,554,432
#define WS_NEED  ((size_t)P_OFF + P_BYTES)

#define AS1(p) ((const __attribute__((address_space(1))) void*)(p))
#define AS3(p) ((__attribute__((address_space(3))) void*)(p))

// ---------- merged prep: x pad+f16, W_t, W_o_t ----------
__global__ __launch_bounds__(256) void prep_all(const float* __restrict__ x,
        const float* __restrict__ dw, const float* __restrict__ ow,
        __half* __restrict__ xp, __half* __restrict__ wt, __half* __restrict__ wot) {
    int b = blockIdx.x, tid = threadIdx.x;
    if (b < 2245) {                               // x_p
        int g = b * 256 + tid;
        if (g >= 17956 * 32) return;
        int row = g >> 5, sub = g & 31;
        int n = row / 4489, rem = row - n * 4489;
        int yy = rem / 67,  xx = rem - yy * 67;
        __half* dst = xp + (size_t)row * 256 + sub * 8;
        union { uint4 u; __half2 h[4]; } r;
        r.u = make_uint4(0u, 0u, 0u, 0u);
        if (yy >= 1 && yy <= 64 && xx >= 1 && xx <= 64) {
            const float* src = x + (((size_t)n * 64 + (yy - 1)) * 64 + (xx - 1)) * 256 + sub * 8;
            float4 a = *(const float4*)src;
            float4 c = *(const float4*)(src + 4);
            r.h[0] = __float22half2_rn(make_float2(a.x, a.y));
            r.h[1] = __float22half2_rn(make_float2(a.z, a.w));
            r.h[2] = __float22half2_rn(make_float2(c.x, c.y));
            r.h[3] = __float22half2_rn(make_float2(c.z, c.w));
        }
        *(uint4*)dst = r.u;
    } else if (b < 2501) {                        // W_t[oc][t*256+c] = dcn_w[oc][c][t]
        int oc = b - 2245, c = tid;
        const float* src = dw + oc * 2304 + c * 9;
        __half* dst = wt + oc * 2304 + c;
        #pragma unroll
        for (int t = 0; t < 9; ++t) dst[t * 256] = __float2half(src[t]);
    } else {                                      // W_o_t
        int g = (b - 2501) * 256 + tid;           // < 73728
        int oc = g & 31, idx = g >> 5;
        float v = (oc < 27) ? ow[idx * 27 + oc] : 0.f;
        wot[oc * 2304 + idx] = __float2half(v);
    }
}

// ---------- offset conv: 32 px x 32 oc, A staged via global_load_lds ----------
__global__ __launch_bounds__(256) void offset_mfma4(const __half* __restrict__ xp,
        const __half* __restrict__ wot, const float* __restrict__ ob,
        float* __restrict__ om) {
    __shared__ __align__(16) char sA[2][16384];
    int tid = threadIdx.x, lane = tid & 63, wave = tid >> 6;
    int bid = blockIdx.x;
    int mt = (bid & 7) * 64 + (bid >> 3);         // XCD-bijective (512 blocks)
    int p0 = mt * 32;
    int n = p0 >> 12, y = (p0 & 4095) >> 6, w0 = p0 & 63;
    const char* xpn = (const char*)(xp + (size_t)n * 4489 * 256);
    int wr = wave >> 1, wc = wave & 1;
    int ar = lane & 15, kl = (lane >> 4) * 8;

    int soff[4];
    #pragma unroll
    for (int q = 0; q < 4; ++q) {
        int d = (q * 256 + tid) * 16;
        int row = d >> 9;
        soff[q] = row * 512 + ((d & 511) ^ ((row & 7) << 4));
    }

    f32x4 acc = {0.f, 0.f, 0.f, 0.f};
    int r_a = wr * 16 + ar;
    int rsw = (r_a & 7) << 4;
    const __half* bb = wot + (size_t)(wc * 16 + ar) * 2304 + kl;

    #pragma unroll
    for (int q = 0; q < 4; ++q)
        __builtin_amdgcn_global_load_lds(AS1(xpn + ((y * 67 + w0) << 9) + soff[q]),
                                         AS3(&sA[0][(q * 256 + tid) * 16]), 16, 0, 0);
    __syncthreads();

    for (int t = 0; t < 9; ++t) {
        int buf = t & 1;
        if (t < 8) {
            int t1 = t + 1;
            int ty = t1 / 3, tx = t1 - 3 * ty;
            int sb = ((y + ty) * 67 + w0 + tx) << 9;
            #pragma unroll
            for (int q = 0; q < 4; ++q)
                __builtin_amdgcn_global_load_lds(AS1(xpn + sb + soff[q]),
                                                 AS3(&sA[buf ^ 1][(q * 256 + tid) * 16]), 16, 0, 0);
        }
        const __half* bp = bb + t * 256;
        #pragma unroll
        for (int c0 = 0; c0 < 256; c0 += 32) {
            f16x8 a = *(const f16x8*)(&sA[buf][0] + r_a * 512 + (((c0 + kl) * 2) ^ rsw));
            f16x8 bfr = *(const f16x8*)(bp + c0);
            acc = __builtin_amdgcn_mfma_f32_16x16x32_f16(a, bfr, acc, 0, 0, 0);
        }
        __syncthreads();
    }

    int col = wc * 16 + ar;
    float bias = (col < 27) ? ob[col] : 0.f;
    int rj = (lane >> 4) * 4;
    #pragma unroll
    for (int j = 0; j < 4; ++j)
        om[(size_t)(p0 + wr * 16 + rj + j) * 32 + col] = acc[j] + bias;
}

// ---------- sampler: V[p][t*256+c] = mask * bilinear(x_p) ----------
// XCD-aligned: block remap so XCD k produces pixels [k*2048,(k+1)*2048) (matches gemm).
__global__ __launch_bounds__(256) void sample_v(const __half* __restrict__ xp,
        const float* __restrict__ om, __half* __restrict__ V) {
    int bid = blockIdx.x;                      // 18432 = 8 * 2304
    int gb  = (bid & 7) * 2304 + (bid >> 3);
    int g = gb * 256 + threadIdx.x;            // < 4,718,592
    int j = g >> 5;
    int s = g & 31;
    int p = j / 9;
    int t = j - p * 9;
    int n = p >> 12, y = (p >> 6) & 63, w = p & 63;
    const float* omp = om + (size_t)p * 32;
    float offy = omp[2 * t];
    float offx = omp[2 * t + 1];
    float mraw = omp[18 + t];
    float mask = 1.f / (1.f + __expf(-mraw));
    float py = (float)(y + 1) + (float)(t / 3 - 1) + offy;
    float px = (float)(w + 1) + (float)(t % 3 - 1) + offx;
    py = fminf(fmaxf(py, 0.f), 65.f);
    px = fminf(fmaxf(px, 0.f), 65.f);
    float y1f = floorf(py), x1f = floorf(px);
    int y1 = (int)y1f, x1 = (int)x1f;
    float ly = py - y1f, lx = px - x1f, hy = 1.f - ly, hx = 1.f - lx;
    const __half* b = xp + (size_t)n * 4489 * 256 + ((y1 * 67 + x1) << 8) + s * 8;
    union { uint4 u; __half2 h[4]; } cA, cB, cC, cD, r;
    cA.u = *(const uint4*)(b);
    cB.u = *(const uint4*)(b + 256);
    cC.u = *(const uint4*)(b + 17152);     // +1 row (67*256)
    cD.u = *(const uint4*)(b + 17408);
    __half2 W11 = __float2half2_rn(hy * hx * mask), W12 = __float2half2_rn(hy * lx * mask);
    __half2 W21 = __float2half2_rn(ly * hx * mask), W22 = __float2half2_rn(ly * lx * mask);
    #pragma unroll
    for (int i = 0; i < 4; ++i)
        r.h[i] = __hfma2(cD.h[i], W22, __hfma2(cC.h[i], W21,
                 __hfma2(cB.h[i], W12, __hmul2(cA.h[i], W11))));
    *(uint4*)((char*)V + (size_t)g * 16) = r.u;
}

// ---------- GEMM (K-split 2): P[ks][16384,256] = V[:,ks*1152+..] x W^T ----------
// 64x128 tile, BK=64, 4 waves (2x2; each 32x64 = 2x4 frags), dbuf 48KB LDS,
// grid 1024 = 4 blocks/CU nominal (3 resident by LDS), XCD-co-located (mt,nt,ks).
__global__ __launch_bounds__(256) void gemm_ks(const __half* __restrict__ V,
        const __half* __restrict__ wt, float* __restrict__ P) {
    __shared__ __align__(16) char sA[2][8192];    // [64 row][128B]
    __shared__ __align__(16) char sB[2][16384];   // [128 row][128B]
    int tid = threadIdx.x, lane = tid & 63, wave = tid >> 6;
    int bid = blockIdx.x;                          // 1024
    int xcd = bid & 7, idx = bid >> 3;             // idx < 128
    int mt = xcd * 32 + (idx >> 2);                // pixels [xcd*2048, ...)
    int nt = (idx >> 1) & 1;
    int ks = idx & 1;
    int p0 = mt * 64, oc0 = nt * 128;
    int wr = wave >> 1, wc = wave & 1;
    int ar = lane & 15, kl = (lane >> 4) * 8;
    size_t ksb = (size_t)ks * 2304;                // byte offset of K-half (1152 halfs)

    // staging sources (pre-XOR-swizzled, m173); dest linear (q*256+tid)*16
    const char* aS[2]; const char* bS[4];
    #pragma unroll
    for (int q = 0; q < 2; ++q) {
        int d = (q * 256 + tid) * 16;
        int row = d >> 7, wb = d & 127;
        aS[q] = (const char*)V + (size_t)(p0 + row) * 4608 + ksb + (wb ^ ((row & 7) << 4));
    }
    #pragma unroll
    for (int q = 0; q < 4; ++q) {
        int d = (q * 256 + tid) * 16;
        int row = d >> 7, wb = d & 127;
        bS[q] = (const char*)wt + (size_t)(oc0 + row) * 4608 + ksb + (wb ^ ((row & 7) << 4));
    }

    f32x4 acc[2][4];
    #pragma unroll
    for (int m = 0; m < 2; ++m)
        #pragma unroll
        for (int nn = 0; nn < 4; ++nn) acc[m][nn] = (f32x4){0.f,0.f,0.f,0.f};

    #pragma unroll
    for (int q = 0; q < 2; ++q)
        __builtin_amdgcn_global_load_lds(AS1(aS[q]), AS3(&sA[0][(q * 256 + tid) * 16]), 16, 0, 0);
    #pragma unroll
    for (int q = 0; q < 4; ++q)
        __builtin_amdgcn_global_load_lds(AS1(bS[q]), AS3(&sB[0][(q * 256 + tid) * 16]), 16, 0, 0);
    __syncthreads();

    for (int kt = 0; kt < 18; ++kt) {
        int buf = kt & 1;
        if (kt < 17) {
            int kb = (kt + 1) * 128;
            #pragma unroll
            for (int q = 0; q < 2; ++q)
                __builtin_amdgcn_global_load_lds(AS1(aS[q] + kb), AS3(&sA[buf ^ 1][(q * 256 + tid) * 16]), 16, 0, 0);
            #pragma unroll
            for (int q = 0; q < 4; ++q)
                __builtin_amdgcn_global_load_lds(AS1(bS[q] + kb), AS3(&sB[buf ^ 1][(q * 256 + tid) * 16]), 16, 0, 0);
        }
        #pragma unroll
        for (int kk = 0; kk < 2; ++kk) {
            int ko = kk * 64 + kl * 2;
            f16x8 af[2], bf[4];
            #pragma unroll
            for (int m = 0; m < 2; ++m) {
                int r = wr * 32 + m * 16 + ar;
                af[m] = *(const f16x8*)(&sA[buf][0] + r * 128 + (ko ^ ((r & 7) << 4)));
            }
            #pragma unroll
            for (int nn = 0; nn < 4; ++nn) {
                int r = wc * 64 + nn * 16 + ar;
                bf[nn] = *(const f16x8*)(&sB[buf][0] + r * 128 + (ko ^ ((r & 7) << 4)));
            }
            #pragma unroll
            for (int m = 0; m < 2; ++m)
                #pragma unroll
                for (int nn = 0; nn < 4; ++nn)
                    acc[m][nn] = __builtin_amdgcn_mfma_f32_16x16x32_f16(af[m], bf[nn], acc[m][nn], 0, 0, 0);
        }
        __syncthreads();
    }

    // C/D: col=lane&15 (oc), row=(lane>>4)*4+j (px); write K-half partial
    float* Pk = P + (size_t)ks * 16384 * 256;
    int rj = (lane >> 4) * 4;
    #pragma unroll
    for (int m = 0; m < 2; ++m)
        #pragma unroll
        for (int nn = 0; nn < 4; ++nn)
            #pragma unroll
            for (int j = 0; j < 4; ++j)
                Pk[(size_t)(p0 + wr * 32 + m * 16 + rj + j) * 256 + oc0 + wc * 64 + nn * 16 + ar] = acc[m][nn][j];
}

// ---------- reduce: out = P0 + P1 (4,194,304 floats) ----------
__global__ __launch_bounds__(256) void reduce_p(const float* __restrict__ P,
        float* __restrict__ out) {
    int g = blockIdx.x * 256 + threadIdx.x;       // < 262144
    const float4* p0 = (const float4*)P;
    const float4* p1 = (const float4*)(P + (size_t)16384 * 256);
    float4* o = (float4*)out;
    #pragma unroll
    for (int i = 0; i < 4; ++i) {
        int idx = g * 4 + i;
        float4 a = p0[idx], b = p1[idx];
        o[idx] = make_float4(a.x + b.x, a.y + b.y, a.z + b.z, a.w + b.w);
    }
}

// ---------- fallback fused kernel if ws too small ----------
__global__ __launch_bounds__(512) void dcn_mfma3(const __half* __restrict__ xp,
        const float* __restrict__ om, const __half* __restrict__ wt,
        float* __restrict__ out) {
    __shared__ char  s_v[16 * 512];
    __shared__ float s_ly[16][9], s_lx[16][9], s_m[16][9];
    __shared__ int   s_y1[16][9], s_x1[16][9];
    int tid  = threadIdx.x;
    int lane = tid & 63;
    int wave = tid >> 6;
    int bid  = blockIdx.x;
    int swzb = (bid & 7) * 128 + (bid >> 3);
    int p0 = swzb * 16;
    int n  = p0 >> 12;
    int y  = (p0 & 4095) >> 6;
    int w0 = p0 & 63;
    const __half* xpn = xp + (size_t)n * 4489 * 256;
    if (tid < 144) {
        int ps = tid / 9, k = tid - 9 * ps;
        int p  = p0 + ps;
        float offy = om[(size_t)p * 32 + 2 * k];
        float offx = om[(size_t)p * 32 + 2 * k + 1];
        float mraw = om[(size_t)p * 32 + 18 + k];
        float mask = 1.f / (1.f + __expf(-mraw));
        float py = (float)(y + 1)       + (float)(k / 3 - 1) + offy;
        float px = (float)(w0 + ps + 1) + (float)(k % 3 - 1) + offx;
        py = fminf(fmaxf(py, 0.f), 65.f);
        px = fminf(fmaxf(px, 0.f), 65.f);
        float y1f = floorf(py), x1f = floorf(px);
        s_y1[ps][k] = (int)y1f;
        s_x1[ps][k] = (int)x1f;
        s_ly[ps][k] = py - y1f;
        s_lx[ps][k] = px - x1f;
        s_m [ps][k] = mask;
    }
    __syncthreads();
    int px = tid >> 5;
    int ch = (tid & 31) * 8;
    int ar = lane & 15;
    int kl = (lane >> 4) * 8;
    int oc0 = wave * 32;
    const __half* bp0 = wt + (size_t)(oc0 + ar) * 2304 + kl;
    const __half* bp1 = wt + (size_t)(oc0 + 16 + ar) * 2304 + kl;
    int wr_off = px * 512 + (((tid & 31) * 16) ^ ((px & 7) << 4));
    int rd_row = ar * 512;
    int rd_swz = (ar & 7) << 4;
    f32x4 acc0 = {0.f,0.f,0.f,0.f}, acc1 = {0.f,0.f,0.f,0.f};
    for (int t = 0; t < 9; ++t) {
        int y1 = s_y1[px][t], x1 = s_x1[px][t];
        const __half* b = xpn + ((size_t)(y1 * 67 + x1) << 8) + ch;
        union { uint4 u; __half2 h[4]; } cA, cB, cC, cD, r;
        cA.u = *(const uint4*)(b);
        cB.u = *(const uint4*)(b + 256);
        cC.u = *(const uint4*)(b + 17152);
        cD.u = *(const uint4*)(b + 17408);
        float ly = s_ly[px][t], lx = s_lx[px][t], mk = s_m[px][t];
        float hy = 1.f - ly, hx = 1.f - lx;
        __half2 W11 = __float2half2_rn(hy * hx * mk);
        __half2 W12 = __float2half2_rn(hy * lx * mk);
        __half2 W21 = __float2half2_rn(ly * hx * mk);
        __half2 W22 = __float2half2_rn(ly * lx * mk);
        #pragma unroll
        for (int i = 0; i < 4; ++i)
            r.h[i] = __hfma2(cD.h[i], W22, __hfma2(cC.h[i], W21,
                     __hfma2(cB.h[i], W12, __hmul2(cA.h[i], W11))));
        *(uint4*)(s_v + wr_off) = r.u;
        __syncthreads();
        const __half* b0 = bp0 + t * 256;
        const __half* b1 = bp1 + t * 256;
        #pragma unroll
        for (int c0 = 0; c0 < 256; c0 += 32) {
            f16x8 a   = *(const f16x8*)(s_v + rd_row + (((c0 + kl) * 2) ^ rd_swz));
            f16x8 vb0 = *(const f16x8*)(b0 + c0);
            f16x8 vb1 = *(const f16x8*)(b1 + c0);
            acc0 = __builtin_amdgcn_mfma_f32_16x16x32_f16(a, vb0, acc0, 0, 0, 0);
            acc1 = __builtin_amdgcn_mfma_f32_16x16x32_f16(a, vb1, acc1, 0, 0, 0);
        }
        __syncthreads();
    }
    int rj = (lane >> 4) * 4;
    #pragma unroll
    for (int j = 0; j < 4; ++j) {
        out[(size_t)(p0 + rj + j) * 256 + oc0 + ar]      = acc0[j];
        out[(size_t)(p0 + rj + j) * 256 + oc0 + 16 + ar] = acc1[j];
    }
}

extern "C" void kernel_launch(void* const* d_in, const int* in_sizes, int n_in,
                              void* d_out, int out_size, void* d_ws, size_t ws_size,
                              hipStream_t stream) {
    const float* x  = (const float*)d_in[0];
    const float* ow = (const float*)d_in[1];
    const float* ob = (const float*)d_in[2];
    const float* dw = (const float*)d_in[3];
    __half* xpp = (__half*)((char*)d_ws + XP_OFF);
    __half* wt  = (__half*)((char*)d_ws + WT_OFF);
    __half* wot = (__half*)((char*)d_ws + WOT_OFF);
    float*  omp = (float*)((char*)d_ws + OM_OFF);
    __half* Vp  = (__half*)((char*)d_ws + V_OFF);
    float*  Pp  = (float*)((char*)d_ws + P_OFF);
    float* out = (float*)d_out;

    hipLaunchKernelGGL(prep_all,     dim3(2789), dim3(256), 0, stream, x, dw, ow, xpp, wt, wot);
    hipLaunchKernelGGL(offset_mfma4, dim3(512),  dim3(256), 0, stream, xpp, wot, ob, omp);
    if (ws_size >= WS_NEED) {
        hipLaunchKernelGGL(sample_v, dim3(18432), dim3(256), 0, stream, xpp, omp, Vp);
        hipLaunchKernelGGL(gemm_ks,  dim3(1024),  dim3(256), 0, stream, Vp, wt, Pp);
        hipLaunchKernelGGL(reduce_p, dim3(1024),  dim3(256), 0, stream, Pp, out);
    } else {
        hipLaunchKernelGGL(dcn_mfma3, dim3(1024), dim3(512), 0, stream, xpp, omp, wt, out);
    }
}

// Round 9
// 81.327 us; speedup vs baseline: 1.1912x; 1.1912x over previous
//
#include <hip/hip_runtime.h>
#include <hip/hip_fp16.h>
#include <math.h>

typedef __attribute__((ext_vector_type(8))) _Float16 f16x8;
typedef __attribute__((ext_vector_type(4))) float f32x4;

// x (4,64,64,256) f32 | offset_w (3,3,256,27) | offset_b (27) | dcn_weight (256,256,3,3)
// out (4,64,64,256) f32
// ws layout (bytes):
#define XP_OFF   0                        // x_p f16 [4][67][67][256], pad top/left 1, bot/right 2
#define XP_BYTES (4*67*67*256*2)          // 9,193,472
#define WT_OFF   XP_BYTES                 // W_t f16 [256 oc][2304 k], k = t*256+c
#define WT_BYTES (2304*256*2)
#define WOT_OFF  (WT_OFF + WT_BYTES)      // W_o_t f16 [32 oc][2304 k]
#define WOT_BYTES (2304*32*2)
#define OM_OFF   (WOT_OFF + WOT_BYTES)    // om f32 [16384][32]
#define OM_BYTES (16384*32*4)
#define V_OFF    (OM_OFF + OM_BYTES)      // V f16 [16384 px][2304 k]
#define V_BYTES  ((size_t)16384*2304*2)   // 75,497,472
#define WS_NEED  ((size_t)V_OFF + V_BYTES)

#define AS1(p) ((const __attribute__((address_space(1))) void*)(p))
#define AS3(p) ((__attribute__((address_space(3))) void*)(p))

// ---------- merged prep: x pad+f16, W_t, W_o_t ----------
__global__ __launch_bounds__(256) void prep_all(const float* __restrict__ x,
        const float* __restrict__ dw, const float* __restrict__ ow,
        __half* __restrict__ xp, __half* __restrict__ wt, __half* __restrict__ wot) {
    int b = blockIdx.x, tid = threadIdx.x;
    if (b < 2245) {                               // x_p
        int g = b * 256 + tid;
        if (g >= 17956 * 32) return;
        int row = g >> 5, sub = g & 31;
        int n = row / 4489, rem = row - n * 4489;
        int yy = rem / 67,  xx = rem - yy * 67;
        __half* dst = xp + (size_t)row * 256 + sub * 8;
        union { uint4 u; __half2 h[4]; } r;
        r.u = make_uint4(0u, 0u, 0u, 0u);
        if (yy >= 1 && yy <= 64 && xx >= 1 && xx <= 64) {
            const float* src = x + (((size_t)n * 64 + (yy - 1)) * 64 + (xx - 1)) * 256 + sub * 8;
            float4 a = *(const float4*)src;
            float4 c = *(const float4*)(src + 4);
            r.h[0] = __float22half2_rn(make_float2(a.x, a.y));
            r.h[1] = __float22half2_rn(make_float2(a.z, a.w));
            r.h[2] = __float22half2_rn(make_float2(c.x, c.y));
            r.h[3] = __float22half2_rn(make_float2(c.z, c.w));
        }
        *(uint4*)dst = r.u;
    } else if (b < 2501) {                        // W_t[oc][t*256+c] = dcn_w[oc][c][t]
        int oc = b - 2245, c = tid;
        const float* src = dw + oc * 2304 + c * 9;
        __half* dst = wt + oc * 2304 + c;
        #pragma unroll
        for (int t = 0; t < 9; ++t) dst[t * 256] = __float2half(src[t]);
    } else {                                      // W_o_t
        int g = (b - 2501) * 256 + tid;           // < 73728
        int oc = g & 31, idx = g >> 5;
        float v = (oc < 27) ? ow[idx * 27 + oc] : 0.f;
        wot[oc * 2304 + idx] = __float2half(v);
    }
}

// ---------- offset conv: 32 px x 32 oc, A staged via global_load_lds ----------
__global__ __launch_bounds__(256) void offset_mfma4(const __half* __restrict__ xp,
        const __half* __restrict__ wot, const float* __restrict__ ob,
        float* __restrict__ om) {
    __shared__ __align__(16) char sA[2][16384];
    int tid = threadIdx.x, lane = tid & 63, wave = tid >> 6;
    int bid = blockIdx.x;
    int mt = (bid & 7) * 64 + (bid >> 3);         // XCD-bijective (512 blocks)
    int p0 = mt * 32;
    int n = p0 >> 12, y = (p0 & 4095) >> 6, w0 = p0 & 63;
    const char* xpn = (const char*)(xp + (size_t)n * 4489 * 256);
    int wr = wave >> 1, wc = wave & 1;
    int ar = lane & 15, kl = (lane >> 4) * 8;

    int soff[4];
    #pragma unroll
    for (int q = 0; q < 4; ++q) {
        int d = (q * 256 + tid) * 16;
        int row = d >> 9;
        soff[q] = row * 512 + ((d & 511) ^ ((row & 7) << 4));
    }

    f32x4 acc = {0.f, 0.f, 0.f, 0.f};
    int r_a = wr * 16 + ar;
    int rsw = (r_a & 7) << 4;
    const __half* bb = wot + (size_t)(wc * 16 + ar) * 2304 + kl;

    #pragma unroll
    for (int q = 0; q < 4; ++q)
        __builtin_amdgcn_global_load_lds(AS1(xpn + ((y * 67 + w0) << 9) + soff[q]),
                                         AS3(&sA[0][(q * 256 + tid) * 16]), 16, 0, 0);
    __syncthreads();

    for (int t = 0; t < 9; ++t) {
        int buf = t & 1;
        if (t < 8) {
            int t1 = t + 1;
            int ty = t1 / 3, tx = t1 - 3 * ty;
            int sb = ((y + ty) * 67 + w0 + tx) << 9;
            #pragma unroll
            for (int q = 0; q < 4; ++q)
                __builtin_amdgcn_global_load_lds(AS1(xpn + sb + soff[q]),
                                                 AS3(&sA[buf ^ 1][(q * 256 + tid) * 16]), 16, 0, 0);
        }
        const __half* bp = bb + t * 256;
        #pragma unroll
        for (int c0 = 0; c0 < 256; c0 += 32) {
            f16x8 a = *(const f16x8*)(&sA[buf][0] + r_a * 512 + (((c0 + kl) * 2) ^ rsw));
            f16x8 bfr = *(const f16x8*)(bp + c0);
            acc = __builtin_amdgcn_mfma_f32_16x16x32_f16(a, bfr, acc, 0, 0, 0);
        }
        __syncthreads();
    }

    int col = wc * 16 + ar;
    float bias = (col < 27) ? ob[col] : 0.f;
    int rj = (lane >> 4) * 4;
    #pragma unroll
    for (int j = 0; j < 4; ++j)
        om[(size_t)(p0 + wr * 16 + rj + j) * 32 + col] = acc[j] + bias;
}

// ---------- sampler: V[p][t*256+c] = mask * bilinear(x_p) ----------
// XCD-aligned: block remap so XCD k produces pixels [k*2048,(k+1)*2048) (matches gemm).
__global__ __launch_bounds__(256) void sample_v(const __half* __restrict__ xp,
        const float* __restrict__ om, __half* __restrict__ V) {
    int bid = blockIdx.x;                      // 18432 = 8 * 2304
    int gb  = (bid & 7) * 2304 + (bid >> 3);
    int g = gb * 256 + threadIdx.x;            // < 4,718,592
    int j = g >> 5;
    int s = g & 31;
    int p = j / 9;
    int t = j - p * 9;
    int n = p >> 12, y = (p >> 6) & 63, w = p & 63;
    const float* omp = om + (size_t)p * 32;
    float offy = omp[2 * t];
    float offx = omp[2 * t + 1];
    float mraw = omp[18 + t];
    float mask = 1.f / (1.f + __expf(-mraw));
    float py = (float)(y + 1) + (float)(t / 3 - 1) + offy;
    float px = (float)(w + 1) + (float)(t % 3 - 1) + offx;
    py = fminf(fmaxf(py, 0.f), 65.f);
    px = fminf(fmaxf(px, 0.f), 65.f);
    float y1f = floorf(py), x1f = floorf(px);
    int y1 = (int)y1f, x1 = (int)x1f;
    float ly = py - y1f, lx = px - x1f, hy = 1.f - ly, hx = 1.f - lx;
    const __half* b = xp + (size_t)n * 4489 * 256 + ((y1 * 67 + x1) << 8) + s * 8;
    union { uint4 u; __half2 h[4]; } cA, cB, cC, cD, r;
    cA.u = *(const uint4*)(b);
    cB.u = *(const uint4*)(b + 256);
    cC.u = *(const uint4*)(b + 17152);     // +1 row (67*256)
    cD.u = *(const uint4*)(b + 17408);
    __half2 W11 = __float2half2_rn(hy * hx * mask), W12 = __float2half2_rn(hy * lx * mask);
    __half2 W21 = __float2half2_rn(ly * hx * mask), W22 = __float2half2_rn(ly * lx * mask);
    #pragma unroll
    for (int i = 0; i < 4; ++i)
        r.h[i] = __hfma2(cD.h[i], W22, __hfma2(cC.h[i], W21,
                 __hfma2(cB.h[i], W12, __hmul2(cA.h[i], W11))));
    *(uint4*)((char*)V + (size_t)g * 16) = r.u;
}

// ---------- GEMM: out[16384,256] = V[16384,2304] x W_t[256,2304]^T ----------
// 64x128 tile, BK=64, 4 waves (2x2; each 32x64 = 2x4 frags).
// T4 counted-vmcnt pipeline: triple-buffered LDS (3 x 24KB), stage depth 3,
// vmcnt never drained to 0 in the main loop; raw s_barrier (no implicit drain).
#define WAITVM(N) do { asm volatile("s_waitcnt vmcnt(" #N ")" ::: "memory"); \
                       __builtin_amdgcn_sched_barrier(0); } while (0)

#define STAGE_V4(BUF, KT) do { \
    _Pragma("unroll") \
    for (int q = 0; q < 2; ++q) \
        __builtin_amdgcn_global_load_lds(AS1(aS[q] + (size_t)(KT) * 128), \
            AS3(&sA[BUF][(q * 256 + tid) * 16]), 16, 0, 0); \
    _Pragma("unroll") \
    for (int q = 0; q < 4; ++q) \
        __builtin_amdgcn_global_load_lds(AS1(bS[q] + (size_t)(KT) * 128), \
            AS3(&sB[BUF][(q * 256 + tid) * 16]), 16, 0, 0); \
} while (0)

#define COMPUTE_V4(BUF) do { \
    _Pragma("unroll") \
    for (int kk = 0; kk < 2; ++kk) { \
        int ko = kk * 64 + kl * 2; \
        f16x8 af[2], bf[4]; \
        _Pragma("unroll") \
        for (int m = 0; m < 2; ++m) { \
            int r = wr * 32 + m * 16 + ar; \
            af[m] = *(const f16x8*)(&sA[BUF][0] + r * 128 + (ko ^ ((r & 7) << 4))); \
        } \
        _Pragma("unroll") \
        for (int nn = 0; nn < 4; ++nn) { \
            int r = wc * 64 + nn * 16 + ar; \
            bf[nn] = *(const f16x8*)(&sB[BUF][0] + r * 128 + (ko ^ ((r & 7) << 4))); \
        } \
        __builtin_amdgcn_s_setprio(1); \
        _Pragma("unroll") \
        for (int m = 0; m < 2; ++m) \
            _Pragma("unroll") \
            for (int nn = 0; nn < 4; ++nn) \
                acc[m][nn] = __builtin_amdgcn_mfma_f32_16x16x32_f16(af[m], bf[nn], acc[m][nn], 0, 0, 0); \
        __builtin_amdgcn_s_setprio(0); \
    } \
} while (0)

__global__ __launch_bounds__(256) void gemm_v4(const __half* __restrict__ V,
        const __half* __restrict__ wt, float* __restrict__ out) {
    __shared__ __align__(16) char sA[3][8192];    // [64 row][128B], XOR-swizzled
    __shared__ __align__(16) char sB[3][16384];   // [128 row][128B]
    int tid = threadIdx.x, lane = tid & 63, wave = tid >> 6;
    int bid = blockIdx.x;
    int xcd = bid & 7, idx = bid >> 3;            // 512 blocks
    int mt = xcd * 32 + (idx >> 1);               // XCD k owns pixels [k*2048,(k+1)*2048)
    int nt = idx & 1;
    int p0 = mt * 64, oc0 = nt * 128;
    int wr = wave >> 1, wc = wave & 1;
    int ar = lane & 15, kl = (lane >> 4) * 8;

    // staging sources (pre-XOR-swizzled, m173); dest linear (q*256+tid)*16
    const char* aS[2]; const char* bS[4];
    #pragma unroll
    for (int q = 0; q < 2; ++q) {
        int d = (q * 256 + tid) * 16;
        int row = d >> 7, wb = d & 127;
        aS[q] = (const char*)V + (size_t)(p0 + row) * 4608 + (wb ^ ((row & 7) << 4));
    }
    #pragma unroll
    for (int q = 0; q < 4; ++q) {
        int d = (q * 256 + tid) * 16;
        int row = d >> 7, wb = d & 127;
        bS[q] = (const char*)wt + (size_t)(oc0 + row) * 4608 + (wb ^ ((row & 7) << 4));
    }

    f32x4 acc[2][4];
    #pragma unroll
    for (int m = 0; m < 2; ++m)
        #pragma unroll
        for (int nn = 0; nn < 4; ++nn) acc[m][nn] = (f32x4){0.f,0.f,0.f,0.f};

    // prologue: stage kt = 0,1,2 into bufs 0,1,2 (18 loads in flight/thread)
    STAGE_V4(0, 0);
    STAGE_V4(1, 1);
    STAGE_V4(2, 2);

    // steady state: kt = 0..33  (outstanding: kt, kt+1, kt+2 -> wait to 12)
    for (int kt = 0; kt < 34; ++kt) {
        int buf = kt % 3;
        WAITVM(12);                               // my stage(kt) landed
        __builtin_amdgcn_s_barrier();             // everyone's stage(kt) landed
        __builtin_amdgcn_sched_barrier(0);
        COMPUTE_V4(buf);
        __builtin_amdgcn_s_barrier();             // all waves done reading buf
        STAGE_V4(buf, kt + 3);                    // refill with kt+3
    }
    // kt = 34: outstanding = {34, 35} -> 12 total, wait to 6
    WAITVM(6);
    __builtin_amdgcn_s_barrier();
    __builtin_amdgcn_sched_barrier(0);
    COMPUTE_V4(34 % 3);
    __builtin_amdgcn_s_barrier();
    // kt = 35: outstanding = {35} -> wait to 0
    WAITVM(0);
    __builtin_amdgcn_s_barrier();
    __builtin_amdgcn_sched_barrier(0);
    COMPUTE_V4(35 % 3);

    // C/D: col=lane&15 (oc), row=(lane>>4)*4+j (px)
    int rj = (lane >> 4) * 4;
    #pragma unroll
    for (int m = 0; m < 2; ++m)
        #pragma unroll
        for (int nn = 0; nn < 4; ++nn)
            #pragma unroll
            for (int j = 0; j < 4; ++j)
                out[(size_t)(p0 + wr * 32 + m * 16 + rj + j) * 256 + oc0 + wc * 64 + nn * 16 + ar] = acc[m][nn][j];
}

// ---------- fallback fused kernel if ws too small ----------
__global__ __launch_bounds__(512) void dcn_mfma3(const __half* __restrict__ xp,
        const float* __restrict__ om, const __half* __restrict__ wt,
        float* __restrict__ out) {
    __shared__ char  s_v[16 * 512];
    __shared__ float s_ly[16][9], s_lx[16][9], s_m[16][9];
    __shared__ int   s_y1[16][9], s_x1[16][9];
    int tid  = threadIdx.x;
    int lane = tid & 63;
    int wave = tid >> 6;
    int bid  = blockIdx.x;
    int swzb = (bid & 7) * 128 + (bid >> 3);
    int p0 = swzb * 16;
    int n  = p0 >> 12;
    int y  = (p0 & 4095) >> 6;
    int w0 = p0 & 63;
    const __half* xpn = xp + (size_t)n * 4489 * 256;
    if (tid < 144) {
        int ps = tid / 9, k = tid - 9 * ps;
        int p  = p0 + ps;
        float offy = om[(size_t)p * 32 + 2 * k];
        float offx = om[(size_t)p * 32 + 2 * k + 1];
        float mraw = om[(size_t)p * 32 + 18 + k];
        float mask = 1.f / (1.f + __expf(-mraw));
        float py = (float)(y + 1)       + (float)(k / 3 - 1) + offy;
        float px = (float)(w0 + ps + 1) + (float)(k % 3 - 1) + offx;
        py = fminf(fmaxf(py, 0.f), 65.f);
        px = fminf(fmaxf(px, 0.f), 65.f);
        float y1f = floorf(py), x1f = floorf(px);
        s_y1[ps][k] = (int)y1f;
        s_x1[ps][k] = (int)x1f;
        s_ly[ps][k] = py - y1f;
        s_lx[ps][k] = px - x1f;
        s_m [ps][k] = mask;
    }
    __syncthreads();
    int px = tid >> 5;
    int ch = (tid & 31) * 8;
    int ar = lane & 15;
    int kl = (lane >> 4) * 8;
    int oc0 = wave * 32;
    const __half* bp0 = wt + (size_t)(oc0 + ar) * 2304 + kl;
    const __half* bp1 = wt + (size_t)(oc0 + 16 + ar) * 2304 + kl;
    int wr_off = px * 512 + (((tid & 31) * 16) ^ ((px & 7) << 4));
    int rd_row = ar * 512;
    int rd_swz = (ar & 7) << 4;
    f32x4 acc0 = {0.f,0.f,0.f,0.f}, acc1 = {0.f,0.f,0.f,0.f};
    for (int t = 0; t < 9; ++t) {
        int y1 = s_y1[px][t], x1 = s_x1[px][t];
        const __half* b = xpn + ((size_t)(y1 * 67 + x1) << 8) + ch;
        union { uint4 u; __half2 h[4]; } cA, cB, cC, cD, r;
        cA.u = *(const uint4*)(b);
        cB.u = *(const uint4*)(b + 256);
        cC.u = *(const uint4*)(b + 17152);
        cD.u = *(const uint4*)(b + 17408);
        float ly = s_ly[px][t], lx = s_lx[px][t], mk = s_m[px][t];
        float hy = 1.f - ly, hx = 1.f - lx;
        __half2 W11 = __float2half2_rn(hy * hx * mk);
        __half2 W12 = __float2half2_rn(hy * lx * mk);
        __half2 W21 = __float2half2_rn(ly * hx * mk);
        __half2 W22 = __float2half2_rn(ly * lx * mk);
        #pragma unroll
        for (int i = 0; i < 4; ++i)
            r.h[i] = __hfma2(cD.h[i], W22, __hfma2(cC.h[i], W21,
                     __hfma2(cB.h[i], W12, __hmul2(cA.h[i], W11))));
        *(uint4*)(s_v + wr_off) = r.u;
        __syncthreads();
        const __half* b0 = bp0 + t * 256;
        const __half* b1 = bp1 + t * 256;
        #pragma unroll
        for (int c0 = 0; c0 < 256; c0 += 32) {
            f16x8 a   = *(const f16x8*)(s_v + rd_row + (((c0 + kl) * 2) ^ rd_swz));
            f16x8 vb0 = *(const f16x8*)(b0 + c0);
            f16x8 vb1 = *(const f16x8*)(b1 + c0);
            acc0 = __builtin_amdgcn_mfma_f32_16x16x32_f16(a, vb0, acc0, 0, 0, 0);
            acc1 = __builtin_amdgcn_mfma_f32_16x16x32_f16(a, vb1, acc1, 0, 0, 0);
        }
        __syncthreads();
    }
    int rj = (lane >> 4) * 4;
    #pragma unroll
    for (int j = 0; j < 4; ++j) {
        out[(size_t)(p0 + rj + j) * 256 + oc0 + ar]      = acc0[j];
        out[(size_t)(p0 + rj + j) * 256 + oc0 + 16 + ar] = acc1[j];
    }
}

extern "C" void kernel_launch(void* const* d_in, const int* in_sizes, int n_in,
                              void* d_out, int out_size, void* d_ws, size_t ws_size,
                              hipStream_t stream) {
    const float* x  = (const float*)d_in[0];
    const float* ow = (const float*)d_in[1];
    const float* ob = (const float*)d_in[2];
    const float* dw = (const float*)d_in[3];
    __half* xpp = (__half*)((char*)d_ws + XP_OFF);
    __half* wt  = (__half*)((char*)d_ws + WT_OFF);
    __half* wot = (__half*)((char*)d_ws + WOT_OFF);
    float*  omp = (float*)((char*)d_ws + OM_OFF);
    __half* Vp  = (__half*)((char*)d_ws + V_OFF);
    float* out = (float*)d_out;

    hipLaunchKernelGGL(prep_all,     dim3(2789), dim3(256), 0, stream, x, dw, ow, xpp, wt, wot);
    hipLaunchKernelGGL(offset_mfma4, dim3(512),  dim3(256), 0, stream, xpp, wot, ob, omp);
    if (ws_size >= WS_NEED) {
        hipLaunchKernelGGL(sample_v, dim3(18432), dim3(256), 0, stream, xpp, omp, Vp);
        hipLaunchKernelGGL(gemm_v4,  dim3(512),   dim3(256), 0, stream, Vp, wt, out);
    } else {
        hipLaunchKernelGGL(dcn_mfma3, dim3(1024), dim3(512), 0, stream, xpp, omp, wt, out);
    }
}